// Round 1
// baseline (601.983 us; speedup 1.0000x reference)
//
#include <hip/hip_runtime.h>
#include <cfloat>

#define Bdim 16
#define Vdim 8
#define Sdim 256
#define Kdim 66
#define NSEQ (Bdim * Vdim)              // 128 sequences
#define TPB 256
#define NROW (Bdim * Sdim * Sdim)       // 1048576 argmax rows
#define ARGMAX_BLOCKS (NROW / (2 * TPB))// 2048 (2 rows per thread)

// Fused kernel: blocks [0,NSEQ) do one CRF sequence each; blocks [NSEQ, NSEQ+ARGMAX_BLOCKS)
// stream log_pa and write argmax indices (as float) to out[1..].
__global__ __launch_bounds__(TPB) void crf_fused(
    const float* __restrict__ log_pa,
    const float* __restrict__ score,
    const int*   __restrict__ v_label,
    const int*   __restrict__ orig_l,
    const int*   __restrict__ role_label,
    const float* __restrict__ start_t,
    const float* __restrict__ trans,
    const float* __restrict__ end_t,
    float* __restrict__ out,
    float* __restrict__ ws)
{
  const int tid = threadIdx.x;
  const int bid = blockIdx.x;

  if (bid >= NSEQ) {
    // ---------------- argmax over K, 2 rows (132 floats = 33 float4) per thread ----------------
    const int gt = (bid - NSEQ) * TPB + tid;  // 0..524287
    const float4* p4 = reinterpret_cast<const float4*>(log_pa) + (size_t)gt * 33;
    float best0 = -FLT_MAX, best1 = -FLT_MAX;
    int i0 = 0, i1 = 0;
#pragma unroll
    for (int q = 0; q < 33; ++q) {
      float4 w = p4[q];
      float v[4] = {w.x, w.y, w.z, w.w};
#pragma unroll
      for (int c = 0; c < 4; ++c) {
        int e = 4 * q + c;                 // compile-time after unroll
        if (e < Kdim) {
          if (v[c] > best0) { best0 = v[c]; i0 = e; }
        } else {
          int e1 = e - Kdim;
          if (v[c] > best1) { best1 = v[c]; i1 = e1; }
        }
      }
    }
    float* o = out + 1 + (size_t)gt * 2;
    o[0] = (float)i0;
    o[1] = (float)i1;
    return;
  }

  // ---------------- CRF: one block per sequence ----------------
  __shared__ __align__(16) float sP[Kdim + 2]; // exp(alpha - m), padded for float4 reads
  __shared__ float sRed[TPB];
  __shared__ int   sG[Sdim];
  __shared__ float sM;

  const int n  = bid;
  const int b  = n / Vdim;
  const int v  = n % Vdim;
  const int L  = orig_l[b];                       // prefix mask length, 128..256
  const int sl = v_label[b * Vdim + v];
  const float* logits = score + (size_t)(b * Sdim + sl) * Sdim * Kdim; // [S][K]

  // stage gold labels (one per thread; TPB == Sdim)
  sG[tid] = role_label[(size_t)n * Sdim + tid];

  // per-thread column of E = exp(trans[:, tid]) in registers
  float E[Kdim];
  float alpha = 0.f;
  if (tid < Kdim) {
#pragma unroll
    for (int i = 0; i < Kdim; ++i)
      E[i] = __expf(trans[i * Kdim + tid]);
    alpha = start_t[tid] + logits[tid];           // alpha0
  }
  __syncthreads();

  // gold score partials: emit[t] + trans[g_{t-1}, g_t], t < L
  {
    const int t = tid;
    float c = 0.f;
    if (t < L) {
      int g = sG[t];
      c = logits[t * Kdim + g];
      if (t > 0) c += trans[sG[t - 1] * Kdim + g];
    }
    sRed[tid] = c;
  }
  __syncthreads();
  for (int off = TPB / 2; off > 0; off >>= 1) {
    if (tid < off) sRed[tid] += sRed[tid + off];
    __syncthreads();
  }
  float goldReg = 0.f;
  if (tid == 0)
    goldReg = sRed[0] + start_t[sG[0]] + end_t[sG[L - 1]];

  // forward recursion: alpha'[j] = m + log(sum_i exp(alpha_i - m) * E[i][j]) + logit[t][j]
  const float4* sP4 = reinterpret_cast<const float4*>(sP);
  for (int t = 1; t < L; ++t) {
    float lt = 0.f;
    if (tid < Kdim) lt = logits[t * Kdim + tid];  // prefetch early
    if (tid == 0) sM = alpha;                     // shift = alpha[0] (spread << 88, safe)
    __syncthreads();
    const float m = sM;
    if (tid < Kdim) sP[tid] = __expf(alpha - m);
    __syncthreads();
    if (tid < Kdim) {
      float s0 = 0.f, s1 = 0.f, s2 = 0.f, s3 = 0.f;
#pragma unroll
      for (int q = 0; q < 16; ++q) {
        float4 p = sP4[q];
        s0 = fmaf(p.x, E[4 * q + 0], s0);
        s1 = fmaf(p.y, E[4 * q + 1], s1);
        s2 = fmaf(p.z, E[4 * q + 2], s2);
        s3 = fmaf(p.w, E[4 * q + 3], s3);
      }
      s0 = fmaf(sP[64], E[64], s0);
      s1 = fmaf(sP[65], E[65], s1);
      float s = (s0 + s1) + (s2 + s3);
      alpha = m + __logf(s) + lt;
    }
  }

  // log_z = logsumexp(alpha + end_t)
  __syncthreads();
  if (tid < Kdim) sP[tid] = alpha + end_t[tid];
  __syncthreads();
  if (tid == 0) {
    float mm = -FLT_MAX;
    for (int i = 0; i < Kdim; ++i) mm = fmaxf(mm, sP[i]);
    float ss = 0.f;
    for (int i = 0; i < Kdim; ++i) ss += __expf(sP[i] - mm);
    float logz = mm + __logf(ss);
    ws[n] = goldReg - logz;
  }
}

__global__ void finalize_loss(const float* __restrict__ ws, float* __restrict__ out) {
  __shared__ float r[NSEQ];
  int tid = threadIdx.x;
  r[tid] = ws[tid];
  __syncthreads();
  for (int off = NSEQ / 2; off > 0; off >>= 1) {
    if (tid < off) r[tid] += r[tid + off];
    __syncthreads();
  }
  if (tid == 0) out[0] = r[0] / (float)NSEQ;
}

extern "C" void kernel_launch(void* const* d_in, const int* in_sizes, int n_in,
                              void* d_out, int out_size, void* d_ws, size_t ws_size,
                              hipStream_t stream) {
  const float* log_pa     = (const float*)d_in[0];
  const float* score      = (const float*)d_in[1];
  const int*   v_label    = (const int*)d_in[2];
  // d_in[3] = v_l (unused by reference)
  const int*   orig_l     = (const int*)d_in[4];
  const int*   role_label = (const int*)d_in[5];
  const float* start_t    = (const float*)d_in[6];
  const float* trans      = (const float*)d_in[7];
  const float* end_t      = (const float*)d_in[8];
  float* out = (float*)d_out;
  float* ws  = (float*)d_ws;   // 128 floats of per-sequence llh

  dim3 grid(NSEQ + ARGMAX_BLOCKS);
  crf_fused<<<grid, TPB, 0, stream>>>(log_pa, score, v_label, orig_l, role_label,
                                      start_t, trans, end_t, out, ws);
  finalize_loss<<<1, NSEQ, 0, stream>>>(ws, out);
}

// Round 2
// 533.323 us; speedup vs baseline: 1.1287x; 1.1287x over previous
//
#include <hip/hip_runtime.h>
#include <cfloat>

#define Bdim 16
#define Vdim 8
#define Sdim 256
#define Kdim 66
#define NSEQ 128                       // B*V sequences
#define TPB 256
#define NROW (Bdim * Sdim * Sdim)      // 1048576 argmax rows
#define ROWS_PER_BLK 128
#define AMAX_BLOCKS (NROW / ROWS_PER_BLK)  // 8192
#define CHUNK 64
#define CHUNK_F (CHUNK * Kdim)         // 4224 floats
#define CHUNK_V4 (CHUNK_F / 4)         // 1056 float4

__device__ __forceinline__ void lds_fence_wave() {
  // single-wave LDS ordering: same-wave DS ops execute in order on the LDS
  // pipe; this only stops the compiler from reordering across it.
  asm volatile("" ::: "memory");
  __builtin_amdgcn_wave_barrier();
  asm volatile("" ::: "memory");
}

__global__ __launch_bounds__(TPB) void crf_fused(
    const float* __restrict__ log_pa,
    const float* __restrict__ score,
    const int*   __restrict__ v_label,
    const int*   __restrict__ orig_l,
    const int*   __restrict__ role_label,
    const float* __restrict__ start_t,
    const float* __restrict__ trans,
    const float* __restrict__ end_t,
    float* __restrict__ out,
    float* __restrict__ ws)
{
  __shared__ __align__(16) float sBuf[2][CHUNK_F];  // 33792 B (argmax aliases both)
  __shared__ __align__(16) float sP[68];
  __shared__ float sGoldW[4];
  __shared__ int   sG[Sdim];

  const int tid = threadIdx.x;
  const int bid = blockIdx.x;

  if (bid >= NSEQ) {
    // ---------------- argmax: 128 rows per block, coalesced LDS staging ----------------
    const int ab = bid - NSEQ;                       // 0..8191
    float* sA = &sBuf[0][0];                         // 8448 floats = 128*66
    const float4* g4 = reinterpret_cast<const float4*>(log_pa + (size_t)ab * ROWS_PER_BLK * Kdim);
    float4* s4 = reinterpret_cast<float4*>(sA);
#pragma unroll
    for (int f = tid; f < 2 * CHUNK_V4; f += TPB) s4[f] = g4[f];
    __syncthreads();
    if (tid < ROWS_PER_BLK) {
      const float2* row2 = reinterpret_cast<const float2*>(sA + tid * Kdim); // 66 even -> aligned
      float best = -FLT_MAX; int bi = 0;
#pragma unroll
      for (int q = 0; q < 33; ++q) {
        float2 v = row2[q];
        if (v.x > best) { best = v.x; bi = 2 * q; }
        if (v.y > best) { best = v.y; bi = 2 * q + 1; }
      }
      out[1 + (size_t)ab * ROWS_PER_BLK + tid] = (float)bi;
    }
    return;
  }

  // ---------------- CRF: one block per sequence ----------------
  const int n  = bid;
  const int b  = n / Vdim;
  const int v  = n % Vdim;
  const int L  = orig_l[b];                          // 128..256
  const int sl = v_label[b * Vdim + v];
  const float* logits = score + (size_t)(b * Sdim + sl) * Sdim * Kdim;

  // stage chunk 0 + gold labels
  {
    float4* dst = reinterpret_cast<float4*>(sBuf[0]);
    const float4* src = reinterpret_cast<const float4*>(logits);
    for (int f = tid; f < CHUNK_V4; f += TPB) dst[f] = src[f];
    sG[tid] = role_label[(size_t)n * Sdim + tid];
  }
  __syncthreads();                                   // barrier 1

  const int lane = tid;                              // valid when tid < 64
  float Ecol[Kdim];                                  // E[i][lane], i = 0..65
  float T64 = 0.f, T65 = 0.f, C44 = 0.f, C45 = 0.f, C54 = 0.f, C55 = 0.f;
  float alphaA = 0.f, alpha64 = 0.f, alpha65 = 0.f;

  if (tid < 64) {
    // wave 0: precompute exp(trans) columns + alpha0 (overlaps gold/staging below)
#pragma unroll
    for (int i = 0; i < Kdim; ++i) Ecol[i] = __expf(trans[i * Kdim + lane]);
    T64 = __expf(trans[lane * Kdim + 64]);
    T65 = __expf(trans[lane * Kdim + 65]);
    C44 = __expf(trans[64 * Kdim + 64]); C45 = __expf(trans[64 * Kdim + 65]);
    C54 = __expf(trans[65 * Kdim + 64]); C55 = __expf(trans[65 * Kdim + 65]);
    alphaA = start_t[lane] + sBuf[0][lane];
    if (lane == 0) {
      alpha64 = start_t[64] + sBuf[0][64];
      alpha65 = start_t[65] + sBuf[0][65];
    }
  } else {
    // waves 1-3: gold-score partials (global reads are L2-warm / hidden)
    int idx = tid - 64;                              // 0..191
    float acc = 0.f;
    for (int t = idx; t < Sdim; t += 192) {
      if (t < L) {
        int g = sG[t];
        float e = logits[t * Kdim + g];
        if (t > 0) e += trans[sG[t - 1] * Kdim + g];
        acc += e;
      }
    }
#pragma unroll
    for (int off = 32; off > 0; off >>= 1) acc += __shfl_xor(acc, off, 64);
    if ((tid & 63) == 0) sGoldW[tid >> 6] = acc;     // slots 1..3
  }

  // chunk loop: waves 1-3 stage chunk c+1 while wave 0 computes chunk c
  for (int c = 0; c < 4; ++c) {
    if (tid >= 64) {
      if (c < 3) {
        float4* dst = reinterpret_cast<float4*>(sBuf[(c + 1) & 1]);
        const float4* src = reinterpret_cast<const float4*>(logits + (size_t)(c + 1) * CHUNK_F);
        for (int f = tid - 64; f < CHUNK_V4; f += 192) dst[f] = src[f];
      }
    } else {
      const float* bufc = sBuf[c & 1];
      const int t0 = (c == 0) ? 1 : c * CHUNK;
      const int t1 = min(L, (c + 1) * CHUNK);
      const float4* sP4 = reinterpret_cast<const float4*>(sP);
      for (int t = t0; t < t1; ++t) {
        const float* rowp = bufc + (t - c * CHUNK) * Kdim;
        float lt = rowp[lane];
        float m  = __shfl(alphaA, 0, 64);
        float pA = __expf(alphaA - m);
        float p64 = 0.f, p65 = 0.f;
        sP[lane] = pA;
        if (lane == 0) {
          p64 = __expf(alpha64 - m);
          p65 = __expf(alpha65 - m);
          sP[64] = p64; sP[65] = p65;
        }
        lds_fence_wave();
        float s0 = 0.f, s1 = 0.f, s2 = 0.f, s3 = 0.f;
#pragma unroll
        for (int q = 0; q < 16; ++q) {
          float4 p = sP4[q];                         // same-address broadcast, conflict-free
          s0 = fmaf(p.x, Ecol[4 * q + 0], s0);
          s1 = fmaf(p.y, Ecol[4 * q + 1], s1);
          s2 = fmaf(p.z, Ecol[4 * q + 2], s2);
          s3 = fmaf(p.w, Ecol[4 * q + 3], s3);
        }
        s0 = fmaf(sP[64], Ecol[64], s0);
        s1 = fmaf(sP[65], Ecol[65], s1);
        float dot = (s0 + s1) + (s2 + s3);
        // states 64,65 via butterfly over lanes' pA * E[lane][64/65]
        float s64 = pA * T64, s65 = pA * T65;
#pragma unroll
        for (int off = 32; off > 0; off >>= 1) {
          s64 += __shfl_xor(s64, off, 64);
          s65 += __shfl_xor(s65, off, 64);
        }
        alphaA = m + __logf(dot) + lt;
        if (lane == 0) {
          s64 += p64 * C44 + p65 * C54;
          s65 += p64 * C45 + p65 * C55;
          alpha64 = m + __logf(s64) + rowp[64];
          alpha65 = m + __logf(s65) + rowp[65];
        }
        lds_fence_wave();                            // keep next iter's writes after these reads
      }
    }
    __syncthreads();                                 // chunk boundary (bulk vmcnt drain only)
  }

  // tail: log_z + gold, wave 0 only (no more block barriers)
  if (tid < 64) {
    sP[lane] = alphaA + end_t[lane];
    if (lane == 0) {
      sP[64] = alpha64 + end_t[64];
      sP[65] = alpha65 + end_t[65];
    }
    lds_fence_wave();
    if (lane == 0) {
      float M = -FLT_MAX;
      for (int i = 0; i < Kdim; ++i) M = fmaxf(M, sP[i]);
      float S = 0.f;
      for (int i = 0; i < Kdim; ++i) S += __expf(sP[i] - M);
      float logz = M + __logf(S);
      float gold = sGoldW[1] + sGoldW[2] + sGoldW[3]
                 + start_t[sG[0]] + end_t[sG[L - 1]];
      ws[n] = gold - logz;
    }
  }
}

__global__ void finalize_loss(const float* __restrict__ ws, float* __restrict__ out) {
  __shared__ float r[NSEQ];
  int tid = threadIdx.x;
  r[tid] = ws[tid];
  __syncthreads();
  for (int off = NSEQ / 2; off > 0; off >>= 1) {
    if (tid < off) r[tid] += r[tid + off];
    __syncthreads();
  }
  if (tid == 0) out[0] = r[0] / (float)NSEQ;
}

extern "C" void kernel_launch(void* const* d_in, const int* in_sizes, int n_in,
                              void* d_out, int out_size, void* d_ws, size_t ws_size,
                              hipStream_t stream) {
  const float* log_pa     = (const float*)d_in[0];
  const float* score      = (const float*)d_in[1];
  const int*   v_label    = (const int*)d_in[2];
  // d_in[3] = v_l (unused by reference)
  const int*   orig_l     = (const int*)d_in[4];
  const int*   role_label = (const int*)d_in[5];
  const float* start_t    = (const float*)d_in[6];
  const float* trans      = (const float*)d_in[7];
  const float* end_t      = (const float*)d_in[8];
  float* out = (float*)d_out;
  float* ws  = (float*)d_ws;

  dim3 grid(NSEQ + AMAX_BLOCKS);
  crf_fused<<<grid, TPB, 0, stream>>>(log_pa, score, v_label, orig_l, role_label,
                                      start_t, trans, end_t, out, ws);
  finalize_loss<<<1, NSEQ, 0, stream>>>(ws, out);
}